// Round 6
// baseline (1379.246 us; speedup 1.0000x reference)
//
#include <hip/hip_runtime.h>
#include <hip/hip_bf16.h>
#include <math.h>

#define S_LEN 2048
#define BATCH 2
#define HID 1024
#define NHEAD 16
#define HDIM 64
#define NTOK (S_LEN*BATCH)   // 4096

typedef __bf16 bf16;
typedef __bf16 bf16x4 __attribute__((ext_vector_type(4)));
typedef __bf16 bf16x8 __attribute__((ext_vector_type(8)));
typedef float f32x4 __attribute__((ext_vector_type(4)));

typedef const __attribute__((address_space(1))) unsigned int* gptr_t;
typedef __attribute__((address_space(3))) unsigned int* lptr_t;

__device__ __forceinline__ void gload16(const void* g, void* l) {
    __builtin_amdgcn_global_load_lds((gptr_t)g, (lptr_t)l, 16, 0, 0);
}

// ---------------- fp32 -> bf16 convert (8 elems/thread) ----------------
__global__ void cvt_f32_bf16(const float* __restrict__ src, bf16* __restrict__ dst, int n) {
    int i = (blockIdx.x * blockDim.x + threadIdx.x) * 8;
    if (i >= n) return;
    const float4* s = (const float4*)(src + i);
    float4 a = s[0], b = s[1];
    bf16x8 o;
    o[0] = (bf16)a.x; o[1] = (bf16)a.y; o[2] = (bf16)a.z; o[3] = (bf16)a.w;
    o[4] = (bf16)b.x; o[5] = (bf16)b.y; o[6] = (bf16)b.z; o[7] = (bf16)b.w;
    *(bf16x8*)(dst + i) = o;
}

// ---------------- GEMM: C[M][N] = A[M][K] * B[N][K]^T ----------------
#define BM 128
#define BN 128
#define BK 32

__global__ __launch_bounds__(256) void gemm_bt(
    const bf16* __restrict__ A, const bf16* __restrict__ B,
    int M, int N, int K, int mode,
    const float* __restrict__ bq, const float* __restrict__ bk,
    const float* __restrict__ bv, const float* __restrict__ bo,
    bf16* __restrict__ qh, bf16* __restrict__ kh, bf16* __restrict__ vT,
    float* __restrict__ outp)
{
    __shared__ __align__(16) bf16 As[BM * BK];
    __shared__ __align__(16) bf16 Bs[BN * BK];
    const int tid = threadIdx.x;
    const int lane = tid & 63, wv = tid >> 6;
    const int g = lane >> 4, l15 = lane & 15;
    const int wr = wv >> 1, wc = wv & 1;
    const int bm = blockIdx.y * BM, bn = blockIdx.x * BN;

    f32x4 zero4 = {0.f, 0.f, 0.f, 0.f};
    f32x4 acc[4][4];
#pragma unroll
    for (int mi = 0; mi < 4; mi++)
#pragma unroll
        for (int ni = 0; ni < 4; ni++) acc[mi][ni] = zero4;

    const int r0 = wv * 32 + (lane >> 2);
    const int c0 = (lane & 3) * 8;
    const bf16* Ag0 = A + (size_t)(bm + r0) * K + c0;
    const bf16* Ag1 = Ag0 + (size_t)16 * K;
    const bf16* Bg0 = B + (size_t)(bn + r0) * K + c0;
    const bf16* Bg1 = Bg0 + (size_t)16 * K;
    bf16* AsW = &As[(wv * 32) * BK];
    bf16* BsW = &Bs[(wv * 32) * BK];

    for (int k0 = 0; k0 < K; k0 += BK) {
        gload16(Ag0 + k0, AsW);
        gload16(Ag1 + k0, AsW + 16 * BK);
        gload16(Bg0 + k0, BsW);
        gload16(Bg1 + k0, BsW + 16 * BK);
        __syncthreads();

        bf16x8 aF[4], bF[4];
#pragma unroll
        for (int mi = 0; mi < 4; mi++)
            aF[mi] = *(const bf16x8*)&As[(wr * 64 + mi * 16 + l15) * BK + g * 8];
#pragma unroll
        for (int ni = 0; ni < 4; ni++)
            bF[ni] = *(const bf16x8*)&Bs[(wc * 64 + ni * 16 + l15) * BK + g * 8];
#pragma unroll
        for (int mi = 0; mi < 4; mi++)
#pragma unroll
            for (int ni = 0; ni < 4; ni++)
                acc[mi][ni] = __builtin_amdgcn_mfma_f32_16x16x32_bf16(
                    aF[mi], bF[ni], acc[mi][ni], 0, 0, 0);
        __syncthreads();
    }

    if (mode == 0) {
#pragma unroll
        for (int ni = 0; ni < 4; ni++) {
            int n = bn + wc * 64 + ni * 16 + l15;       // 0..3071
            int which = n >> 10;                         // 0=q 1=k 2=v
            int c = n & 1023;
            int nh = c >> 6, d = c & 63;
            const float* bias_p = (which == 0) ? bq : (which == 1) ? bk : bv;
            float bias = bias_p[c];
            float scl = (which == 0) ? 0.125f : 1.0f;
#pragma unroll
            for (int mi = 0; mi < 4; mi++) {
#pragma unroll
                for (int r = 0; r < 4; r++) {
                    int m = bm + wr * 64 + mi * 16 + g * 4 + r;  // token
                    int s = m >> 1, b = m & 1;
                    int head = b * NHEAD + nh;
                    bf16 val = (bf16)((acc[mi][ni][r] + bias) * scl);
                    if (which == 2)
                        vT[((size_t)(head * HDIM + d)) * S_LEN + s] = val;
                    else {
                        bf16* dst = (which == 0) ? qh : kh;
                        dst[((size_t)(head * S_LEN + s)) * HDIM + d] = val;
                    }
                }
            }
        }
    } else {
#pragma unroll
        for (int ni = 0; ni < 4; ni++) {
            int n = bn + wc * 64 + ni * 16 + l15;
            float bias = bo[n];
#pragma unroll
            for (int mi = 0; mi < 4; mi++) {
#pragma unroll
                for (int r = 0; r < 4; r++) {
                    int m = bm + wr * 64 + mi * 16 + g * 4 + r;
                    outp[(size_t)m * HID + n] = acc[mi][ni][r] + bias;
                }
            }
        }
    }
}

// ---------------- flash attention, ablation-templated ----------------
// VAR 0 = full (real output). VAR 1..5 = diagnostic stubs (timing only):
//   1: no mask stream (no DMA, no mask add)
//   2: no softmax (P = raw scores)
//   3: no QK^T (no K loads / MFMA)
//   4: no PV (no V loads / MFMA)
//   5: no P LDS roundtrip (PV consumes bQ as garbage A-frag)
template<int VAR>
__global__ __launch_bounds__(256, 4) void attn(
    const bf16* __restrict__ q, const bf16* __restrict__ k, const bf16* __restrict__ vT,
    const float* __restrict__ amask,   // [16][2048][2048]
    const float* __restrict__ kmask,   // [32][2048]
    bf16* __restrict__ ctx)            // [4096][1024]
{
    constexpr bool USE_MASK = (VAR != 1);
    constexpr bool USE_SM   = (VAR != 2);
    constexpr bool USE_QK   = (VAR != 3);
    constexpr bool USE_PV   = (VAR != 4);
    constexpr bool USE_P    = (VAR != 5);

    __shared__ __align__(16) float MB0[32 * 64];   // mask tiles (XOR-16B swizzled rows)
    __shared__ __align__(16) float MB1[32 * 64];
    __shared__ __align__(16) float Km0[128];       // kmask [2 b][64 k]
    __shared__ __align__(16) float Km1[128];
    __shared__ __align__(16) bf16 P[4][16][72];    // per-wave P tile

    const int tid = threadIdx.x, lane = tid & 63, wv = tid >> 6;
    const int g = lane >> 4, l15 = lane & 15;
    const int b = wv >> 1, stsub = wv & 1;

    // XCD swizzle: each XCD owns 2 heads -> K/V L2-resident
    const int hw = blockIdx.y * 64 + blockIdx.x;     // grid (64, 16)
    const int vid = (hw & 7) * 128 + (hw >> 3);
    const int nh = vid >> 6;
    const int st0 = (vid & 63) * 32;                 // block q-base (32 rows)
    const int st0s = st0 + stsub * 16;               // wave q-base
    const int n = b * NHEAD + nh;

    // Q fragments (B-operand of swapped QK^T)
    const bf16* qrow = q + ((size_t)(n * S_LEN + st0s + l15)) * HDIM;
    bf16x8 bQ0 = *(const bf16x8*)(qrow + g * 8);
    bf16x8 bQ1 = *(const bf16x8*)(qrow + 32 + g * 8);

    // mask DMA source (per-lane, inverse-swizzled): pass0 rows 0..15, pass1 +16
    const int mrow = tid >> 4;                             // 0..15
    const int mcolf = ((tid & 15) * 4) ^ ((mrow & 7) << 2);
    const float* msrc = amask + ((size_t)nh * S_LEN + st0 + mrow) * S_LEN + mcolf;
    const float* kmsrcW = kmask + (size_t)((wv >> 1) * NHEAD + nh) * S_LEN + lane * 4;

    f32x4 zero4 = {0.f, 0.f, 0.f, 0.f};
    f32x4 O[4];
#pragma unroll
    for (int t = 0; t < 4; t++) O[t] = zero4;
    float mrun = -1e30f, lrun = 0.f;                 // per-lane row q = l15

    const bf16* kbase = k + ((size_t)n * S_LEN + l15) * HDIM + g * 8;
    const bf16* vbase = vT + ((size_t)n * HDIM + l15) * S_LEN + g * 8;
    const int rr = stsub * 16 + l15;                 // mask row this lane consumes

    // ---- prologue: stage tile 0 into MB0/Km0 ----
    if (USE_MASK) {
        gload16(msrc, MB0 + wv * 256);
        gload16(msrc + 16 * S_LEN, MB0 + 1024 + wv * 256);
        if ((wv & 1) == 0 && lane < 16) gload16(kmsrcW, Km0 + (wv >> 1) * 64);
    }
    __syncthreads();

    auto step = [&](int it, const float* MC, const float* KC, float* MN, float* KN) {
        const int tt0 = it * 64;
        // 1. DMA next mask tile
        if (USE_MASK && it < 31) {
            gload16(msrc + tt0 + 64, MN + wv * 256);
            gload16(msrc + tt0 + 64 + 16 * S_LEN, MN + 1024 + wv * 256);
            if ((wv & 1) == 0 && lane < 16) gload16(kmsrcW + tt0 + 64, KN + (wv >> 1) * 64);
        }
        // 2. K loads (global, L2)
        bf16x8 aK[4][2];
        if (USE_QK) {
#pragma unroll
            for (int c = 0; c < 4; c++) {
                const bf16* kp = kbase + (size_t)(tt0 + 16 * c) * HDIM;
                aK[c][0] = *(const bf16x8*)kp;
                aK[c][1] = *(const bf16x8*)(kp + 32);
            }
        }
        // 3. V loads (global, L2) — issued early, live across softmax
        bf16x8 bV[4][2];
        if (USE_PV) {
#pragma unroll
            for (int dt = 0; dt < 4; dt++) {
                const bf16* vp = vbase + (size_t)(dt * 16) * S_LEN + tt0;
                bV[dt][0] = *(const bf16x8*)vp;
                bV[dt][1] = *(const bf16x8*)(vp + 32);
            }
        }
        // 4. QK^T (swapped): sc[c][r] = score(q=l15, k=tt0+16c+4g+r)
        f32x4 sc[4];
#pragma unroll
        for (int c = 0; c < 4; c++) {
            f32x4 s = zero4;
            if (USE_QK) {
                s = __builtin_amdgcn_mfma_f32_16x16x32_bf16(aK[c][0], bQ0, s, 0, 0, 0);
                s = __builtin_amdgcn_mfma_f32_16x16x32_bf16(aK[c][1], bQ1, s, 0, 0, 0);
            }
            sc[c] = s;
        }
        // 5. mask add (LDS, swizzled) + kmask (LDS broadcast)
        if (USE_MASK) {
#pragma unroll
            for (int c = 0; c < 4; c++) {
                int colf = (16 * c + 4 * g) ^ ((rr & 7) << 2);
                f32x4 mk = *(const f32x4*)&MC[rr * 64 + colf];
                f32x4 km = *(const f32x4*)&KC[(wv >> 1) * 64 + 16 * c + 4 * g];
                sc[c] += mk + km;
            }
        }
        // 6. online softmax
        if (USE_SM) {
            float cm = fmaxf(fmaxf(fmaxf(sc[0][0], sc[0][1]), fmaxf(sc[0][2], sc[0][3])),
                             fmaxf(fmaxf(sc[1][0], sc[1][1]), fmaxf(sc[1][2], sc[1][3])));
            cm = fmaxf(cm, fmaxf(fmaxf(fmaxf(sc[2][0], sc[2][1]), fmaxf(sc[2][2], sc[2][3])),
                                 fmaxf(fmaxf(sc[3][0], sc[3][1]), fmaxf(sc[3][2], sc[3][3]))));
            cm = fmaxf(cm, __shfl_xor(cm, 16, 64));
            cm = fmaxf(cm, __shfl_xor(cm, 32, 64));
            if (!__all(cm - mrun <= 8.0f)) {             // defer-max
                float mn = fmaxf(mrun, cm);
                float f = __expf(mrun - mn);
                mrun = mn;
                lrun *= f;
#pragma unroll
                for (int r = 0; r < 4; r++) {
                    float fb = __shfl(f, 4 * g + r, 64);
#pragma unroll
                    for (int dt = 0; dt < 4; dt++) O[dt][r] *= fb;
                }
            }
            float rs = 0.f;
#pragma unroll
            for (int c = 0; c < 4; c++)
#pragma unroll
                for (int r = 0; r < 4; r++) {
                    float p = __expf(sc[c][r] - mrun);
                    sc[c][r] = p;
                    rs += p;
                }
            rs += __shfl_xor(rs, 16, 64);
            rs += __shfl_xor(rs, 32, 64);
            lrun += rs;
        } else {
            lrun += 1.0f;   // keep epilogue sane
        }
        // 7. P -> LDS roundtrip (per-wave)
        bf16x8 aP0, aP1;
        if (USE_P) {
#pragma unroll
            for (int c = 0; c < 4; c++) {
                bf16x4 pk;
                pk[0] = (bf16)sc[c][0]; pk[1] = (bf16)sc[c][1];
                pk[2] = (bf16)sc[c][2]; pk[3] = (bf16)sc[c][3];
                *(bf16x4*)&P[wv][l15][16 * c + 4 * g] = pk;
            }
            asm volatile("s_waitcnt lgkmcnt(0)" ::: "memory");
            __builtin_amdgcn_sched_barrier(0);
            aP0 = *(const bf16x8*)&P[wv][l15][g * 8];
            aP1 = *(const bf16x8*)&P[wv][l15][32 + g * 8];
        } else {
            // keep sc live (rule 17) without the LDS roundtrip
#pragma unroll
            for (int c = 0; c < 4; c++)
                asm volatile("" :: "v"(sc[c][0]), "v"(sc[c][1]), "v"(sc[c][2]), "v"(sc[c][3]));
            aP0 = bQ0; aP1 = bQ1;
        }
        // 8. PV
        if (USE_PV) {
#pragma unroll
            for (int dt = 0; dt < 4; dt++) {
                O[dt] = __builtin_amdgcn_mfma_f32_16x16x32_bf16(aP0, bV[dt][0], O[dt], 0, 0, 0);
                O[dt] = __builtin_amdgcn_mfma_f32_16x16x32_bf16(aP1, bV[dt][1], O[dt], 0, 0, 0);
            }
        } else {
            O[0][0] += (float)aP0[0] + (float)aP1[7];   // keep aP live
        }
        __syncthreads();
    };

#pragma unroll 1
    for (int j = 0; j < 16; ++j) {
        step(2 * j,     MB0, Km0, MB1, Km1);
        step(2 * j + 1, MB1, Km1, MB0, Km0);
    }

    // ---- epilogue ----
#pragma unroll
    for (int r = 0; r < 4; r++) {
        float lq = __shfl(lrun, 4 * g + r, 64);
        float inv = 1.0f / lq;
        int s = st0s + 4 * g + r;
        int token = s * BATCH + b;
#pragma unroll
        for (int dt = 0; dt < 4; dt++) {
            int h = nh * HDIM + dt * 16 + l15;
            ctx[(size_t)token * HID + h] = (bf16)(O[dt][r] * inv);
        }
    }
}

extern "C" void kernel_launch(void* const* d_in, const int* in_sizes, int n_in,
                              void* d_out, int out_size, void* d_ws, size_t ws_size,
                              hipStream_t stream) {
    const float* hidden = (const float*)d_in[0];
    const float* amask  = (const float*)d_in[1];
    const float* kmask  = (const float*)d_in[2];
    const float* Wq = (const float*)d_in[3];
    const float* bq = (const float*)d_in[4];
    const float* Wk = (const float*)d_in[5];
    const float* bk = (const float*)d_in[6];
    const float* Wv = (const float*)d_in[7];
    const float* bv = (const float*)d_in[8];
    const float* Wo = (const float*)d_in[9];
    const float* bo = (const float*)d_in[10];
    float* out = (float*)d_out;

    char* ws = (char*)d_ws;
    bf16* Xb   = (bf16*)(ws);                       // 8 MB  [4096][1024]
    bf16* Wcat = (bf16*)(ws + (8u  << 20));         // 6 MB  [3072][1024]
    bf16* Wob  = (bf16*)(ws + (14u << 20));         // 2 MB  [1024][1024]
    bf16* qh   = (bf16*)(ws + (16u << 20));         // 8 MB  [32][2048][64]
    bf16* kh   = (bf16*)(ws + (24u << 20));         // 8 MB
    bf16* vT   = (bf16*)(ws + (40u << 20));         // 8 MB  [32][64][2048]
    bf16* ctx  = (bf16*)(ws + (48u << 20));         // 8 MB  [4096][1024]

    cvt_f32_bf16<<<2048, 256, 0, stream>>>(hidden, Xb, NTOK * HID);
    cvt_f32_bf16<<<512, 256, 0, stream>>>(Wq, Wcat,              HID * HID);
    cvt_f32_bf16<<<512, 256, 0, stream>>>(Wk, Wcat + HID * HID,  HID * HID);
    cvt_f32_bf16<<<512, 256, 0, stream>>>(Wv, Wcat + 2 * HID * HID, HID * HID);
    cvt_f32_bf16<<<512, 256, 0, stream>>>(Wo, Wob, HID * HID);

    gemm_bt<<<dim3(24, 32), 256, 0, stream>>>(Xb, Wcat, NTOK, 3 * HID, HID, 0,
                                              bq, bk, bv, bo, qh, kh, vT, nullptr);

    // ---- diagnostic ablation dispatches (outputs overwritten by attn<0>) ----
    attn<1><<<dim3(64, 16), 256, 0, stream>>>(qh, kh, vT, amask, kmask, ctx);
    attn<2><<<dim3(64, 16), 256, 0, stream>>>(qh, kh, vT, amask, kmask, ctx);
    attn<3><<<dim3(64, 16), 256, 0, stream>>>(qh, kh, vT, amask, kmask, ctx);
    attn<4><<<dim3(64, 16), 256, 0, stream>>>(qh, kh, vT, amask, kmask, ctx);
    attn<5><<<dim3(64, 16), 256, 0, stream>>>(qh, kh, vT, amask, kmask, ctx);

    // ---- the real attention ----
    attn<0><<<dim3(64, 16), 256, 0, stream>>>(qh, kh, vT, amask, kmask, ctx);

    gemm_bt<<<dim3(8, 32), 256, 0, stream>>>(ctx, Wob, NTOK, HID, HID, 1,
                                             bq, bk, bv, bo, qh, kh, vT, out);
}

// Round 7
// 426.642 us; speedup vs baseline: 3.2328x; 3.2328x over previous
//
#include <hip/hip_runtime.h>
#include <hip/hip_bf16.h>
#include <math.h>

#define S_LEN 2048
#define BATCH 2
#define HID 1024
#define NHEAD 16
#define HDIM 64
#define NTOK (S_LEN*BATCH)   // 4096

typedef __bf16 bf16;
typedef __bf16 bf16x4 __attribute__((ext_vector_type(4)));
typedef __bf16 bf16x8 __attribute__((ext_vector_type(8)));
typedef float f32x4 __attribute__((ext_vector_type(4)));

typedef const __attribute__((address_space(1))) unsigned int* gptr_t;
typedef __attribute__((address_space(3))) unsigned int* lptr_t;

__device__ __forceinline__ void gload16(const void* g, void* l) {
    __builtin_amdgcn_global_load_lds((gptr_t)g, (lptr_t)l, 16, 0, 0);
}

// ---------------- fp32 -> bf16 convert (8 elems/thread) ----------------
__global__ void cvt_f32_bf16(const float* __restrict__ src, bf16* __restrict__ dst, int n) {
    int i = (blockIdx.x * blockDim.x + threadIdx.x) * 8;
    if (i >= n) return;
    const float4* s = (const float4*)(src + i);
    float4 a = s[0], b = s[1];
    bf16x8 o;
    o[0] = (bf16)a.x; o[1] = (bf16)a.y; o[2] = (bf16)a.z; o[3] = (bf16)a.w;
    o[4] = (bf16)b.x; o[5] = (bf16)b.y; o[6] = (bf16)b.z; o[7] = (bf16)b.w;
    *(bf16x8*)(dst + i) = o;
}

// ---------------- GEMM: C[M][N] = A[M][K] * B[N][K]^T ----------------
#define BM 128
#define BN 128
#define BK 32

__global__ __launch_bounds__(256) void gemm_bt(
    const bf16* __restrict__ A, const bf16* __restrict__ B,
    int M, int N, int K, int mode,
    const float* __restrict__ bq, const float* __restrict__ bk,
    const float* __restrict__ bv, const float* __restrict__ bo,
    bf16* __restrict__ qh, bf16* __restrict__ kh, bf16* __restrict__ vT,
    float* __restrict__ outp)
{
    __shared__ __align__(16) bf16 As[BM * BK];
    __shared__ __align__(16) bf16 Bs[BN * BK];
    const int tid = threadIdx.x;
    const int lane = tid & 63, wv = tid >> 6;
    const int g = lane >> 4, l15 = lane & 15;
    const int wr = wv >> 1, wc = wv & 1;
    const int bm = blockIdx.y * BM, bn = blockIdx.x * BN;

    f32x4 zero4 = {0.f, 0.f, 0.f, 0.f};
    f32x4 acc[4][4];
#pragma unroll
    for (int mi = 0; mi < 4; mi++)
#pragma unroll
        for (int ni = 0; ni < 4; ni++) acc[mi][ni] = zero4;

    const int r0 = wv * 32 + (lane >> 2);
    const int c0 = (lane & 3) * 8;
    const bf16* Ag0 = A + (size_t)(bm + r0) * K + c0;
    const bf16* Ag1 = Ag0 + (size_t)16 * K;
    const bf16* Bg0 = B + (size_t)(bn + r0) * K + c0;
    const bf16* Bg1 = Bg0 + (size_t)16 * K;
    bf16* AsW = &As[(wv * 32) * BK];
    bf16* BsW = &Bs[(wv * 32) * BK];

    for (int k0 = 0; k0 < K; k0 += BK) {
        gload16(Ag0 + k0, AsW);
        gload16(Ag1 + k0, AsW + 16 * BK);
        gload16(Bg0 + k0, BsW);
        gload16(Bg1 + k0, BsW + 16 * BK);
        __syncthreads();

        bf16x8 aF[4], bF[4];
#pragma unroll
        for (int mi = 0; mi < 4; mi++)
            aF[mi] = *(const bf16x8*)&As[(wr * 64 + mi * 16 + l15) * BK + g * 8];
#pragma unroll
        for (int ni = 0; ni < 4; ni++)
            bF[ni] = *(const bf16x8*)&Bs[(wc * 64 + ni * 16 + l15) * BK + g * 8];
#pragma unroll
        for (int mi = 0; mi < 4; mi++)
#pragma unroll
            for (int ni = 0; ni < 4; ni++)
                acc[mi][ni] = __builtin_amdgcn_mfma_f32_16x16x32_bf16(
                    aF[mi], bF[ni], acc[mi][ni], 0, 0, 0);
        __syncthreads();
    }

    if (mode == 0) {
#pragma unroll
        for (int ni = 0; ni < 4; ni++) {
            int n = bn + wc * 64 + ni * 16 + l15;       // 0..3071
            int which = n >> 10;                         // 0=q 1=k 2=v
            int c = n & 1023;
            int nh = c >> 6, d = c & 63;
            const float* bias_p = (which == 0) ? bq : (which == 1) ? bk : bv;
            float bias = bias_p[c];
            float scl = (which == 0) ? 0.125f : 1.0f;
#pragma unroll
            for (int mi = 0; mi < 4; mi++) {
#pragma unroll
                for (int r = 0; r < 4; r++) {
                    int m = bm + wr * 64 + mi * 16 + g * 4 + r;  // token
                    int s = m >> 1, b = m & 1;
                    int head = b * NHEAD + nh;
                    bf16 val = (bf16)((acc[mi][ni][r] + bias) * scl);
                    if (which == 2)
                        vT[((size_t)(head * HDIM + d)) * S_LEN + s] = val;
                    else {
                        bf16* dst = (which == 0) ? qh : kh;
                        dst[((size_t)(head * S_LEN + s)) * HDIM + d] = val;
                    }
                }
            }
        }
    } else {
#pragma unroll
        for (int ni = 0; ni < 4; ni++) {
            int n = bn + wc * 64 + ni * 16 + l15;
            float bias = bo[n];
#pragma unroll
            for (int mi = 0; mi < 4; mi++) {
#pragma unroll
                for (int r = 0; r < 4; r++) {
                    int m = bm + wr * 64 + mi * 16 + g * 4 + r;
                    outp[(size_t)m * HID + n] = acc[mi][ni][r] + bias;
                }
            }
        }
    }
}

// ---------------- flash attention: barrier-free, per-wave-private ----------------
// grid 1024 blocks x 4 waves; wave = (b, stsub) fully independent, 16 q-rows each.
// NO __syncthreads anywhere. Per-wave private mask tile (16x64 fp32, single buffer)
// DMA'd one iteration ahead; chunk-XOR swizzle (inverse on DMA source).
// K/V/kmask via register loads (L2-resident thanks to XCD swizzle).
__global__ __launch_bounds__(256, 4) void attn(
    const bf16* __restrict__ q, const bf16* __restrict__ k, const bf16* __restrict__ vT,
    const float* __restrict__ amask,   // [16][2048][2048]
    const float* __restrict__ kmask,   // [32][2048]
    bf16* __restrict__ ctx)            // [4096][1024]
{
    __shared__ __align__(16) float MT[4][16 * 64];   // per-wave mask tile, swizzled
    __shared__ __align__(16) bf16 P[4][16][72];      // per-wave P tile

    const int tid = threadIdx.x, lane = tid & 63, wv = tid >> 6;
    const int g = lane >> 4, l15 = lane & 15;
    const int b = wv >> 1, stsub = wv & 1;

    // XCD swizzle: each XCD owns 2 heads -> K/V L2-resident (2 MB/XCD)
    const int hw = blockIdx.y * 64 + blockIdx.x;     // grid (64, 16)
    const int vid = (hw & 7) * 128 + (hw >> 3);
    const int nh = vid >> 6;
    const int st0 = (vid & 63) * 32;                 // block q-base
    const int st0s = st0 + stsub * 16;               // wave q-base (16 rows)
    const int n = b * NHEAD + nh;

    // Q fragments (B-operand of swapped QK^T)
    const bf16* qrow = q + ((size_t)(n * S_LEN + st0s + l15)) * HDIM;
    bf16x8 bQ0 = *(const bf16x8*)(qrow + g * 8);
    bf16x8 bQ1 = *(const bf16x8*)(qrow + 32 + g * 8);

    // ---- mask DMA addressing (per-wave tile, rows = this wave's 16 q-rows) ----
    // LDS layout: [16 rows][16 chunks f32x4], linear by DMA; logical chunk ch of
    // row r lives at phys chunk ch^(r&7). Inverse applied on the global source.
    const int lrow = lane >> 4;                                  // 0..3
    const int colA = 4 * ((lane & 15) ^ lrow);                   // rows 0-3 / 8-11
    const int colB = 4 * ((lane & 15) ^ (4 + lrow));             // rows 4-7 / 12-15
    const float* msA = amask + ((size_t)nh * S_LEN + st0s + lrow) * S_LEN + colA;
    const float* msB = amask + ((size_t)nh * S_LEN + st0s + lrow) * S_LEN + colB;
    float* mt = &MT[wv][0];

    f32x4 zero4 = {0.f, 0.f, 0.f, 0.f};
    f32x4 O[4];
#pragma unroll
    for (int t = 0; t < 4; t++) O[t] = zero4;
    float mrun = -1e30f, lrun = 0.f;                 // per-lane row q = l15

    const bf16* kbase = k + ((size_t)n * S_LEN + l15) * HDIM + g * 8;
    const bf16* vbase = vT + ((size_t)n * HDIM + l15) * S_LEN + g * 8;
    const float* kmb = kmask + (size_t)n * S_LEN + 4 * g;

    // prologue: stage mask tile 0 (no barrier needed: vmcnt in-order vs K loads)
    gload16(msA,                 mt);
    gload16(msB + 4  * S_LEN,    mt + 256);
    gload16(msA + 8  * S_LEN,    mt + 512);
    gload16(msB + 12 * S_LEN,    mt + 768);

#pragma unroll 1
    for (int tt0 = 0; tt0 < S_LEN; tt0 += 64) {
        // 1. kmask + K register loads (L2)
        f32x4 km[4];
        bf16x8 aK[4][2];
#pragma unroll
        for (int c = 0; c < 4; c++) {
            km[c] = *(const f32x4*)(kmb + tt0 + 16 * c);
            const bf16* kp = kbase + (size_t)(tt0 + 16 * c) * HDIM;
            aK[c][0] = *(const bf16x8*)kp;
            aK[c][1] = *(const bf16x8*)(kp + 32);
        }
        // 2. QK^T (swapped): sc[c][r] = score(q=l15, k=tt0+16c+4g+r)
        //    (auto vmcnt wait for aK also drains the older mask DMA -> LDS valid)
        f32x4 sc[4];
#pragma unroll
        for (int c = 0; c < 4; c++) {
            f32x4 s = zero4;
            s = __builtin_amdgcn_mfma_f32_16x16x32_bf16(aK[c][0], bQ0, s, 0, 0, 0);
            s = __builtin_amdgcn_mfma_f32_16x16x32_bf16(aK[c][1], bQ1, s, 0, 0, 0);
            sc[c] = s;
        }
        // 3. V loads (L2), consumed after softmax — latency hidden
        bf16x8 bV[4][2];
#pragma unroll
        for (int dt = 0; dt < 4; dt++) {
            const bf16* vp = vbase + (size_t)(dt * 16) * S_LEN + tt0;
            bV[dt][0] = *(const bf16x8*)vp;
            bV[dt][1] = *(const bf16x8*)(vp + 32);
        }
        // 4. mask-add from swizzled per-wave LDS tile + kmask regs
#pragma unroll
        for (int c = 0; c < 4; c++) {
            int phys = (4 * c + g) ^ (l15 & 7);
            f32x4 mk = *(const f32x4*)&MT[wv][l15 * 64 + 4 * phys];
            sc[c] += mk + km[c];
        }
        // 5. mask reads retired -> refill the (single) tile for the next iter
        asm volatile("s_waitcnt lgkmcnt(0)" ::: "memory");
        __builtin_amdgcn_sched_barrier(0);
        if (tt0 + 64 < S_LEN) {
            gload16(msA + tt0 + 64,                 mt);
            gload16(msB + tt0 + 64 + 4  * S_LEN,    mt + 256);
            gload16(msA + tt0 + 64 + 8  * S_LEN,    mt + 512);
            gload16(msB + tt0 + 64 + 12 * S_LEN,    mt + 768);
        }
        // 6. online softmax
        float cm = fmaxf(fmaxf(fmaxf(sc[0][0], sc[0][1]), fmaxf(sc[0][2], sc[0][3])),
                         fmaxf(fmaxf(sc[1][0], sc[1][1]), fmaxf(sc[1][2], sc[1][3])));
        cm = fmaxf(cm, fmaxf(fmaxf(fmaxf(sc[2][0], sc[2][1]), fmaxf(sc[2][2], sc[2][3])),
                             fmaxf(fmaxf(sc[3][0], sc[3][1]), fmaxf(sc[3][2], sc[3][3]))));
        cm = fmaxf(cm, __shfl_xor(cm, 16, 64));
        cm = fmaxf(cm, __shfl_xor(cm, 32, 64));
        if (!__all(cm - mrun <= 8.0f)) {             // defer-max (T13)
            float mn = fmaxf(mrun, cm);
            float f = __expf(mrun - mn);
            mrun = mn;
            lrun *= f;
#pragma unroll
            for (int r = 0; r < 4; r++) {
                float fb = __shfl(f, 4 * g + r, 64);
#pragma unroll
                for (int dt = 0; dt < 4; dt++) O[dt][r] *= fb;
            }
        }
        float rs = 0.f;
#pragma unroll
        for (int c = 0; c < 4; c++)
#pragma unroll
            for (int r = 0; r < 4; r++) {
                float p = __expf(sc[c][r] - mrun);
                sc[c][r] = p;
                rs += p;
            }
        rs += __shfl_xor(rs, 16, 64);
        rs += __shfl_xor(rs, 32, 64);
        lrun += rs;
        // 7. P -> per-wave LDS roundtrip (rule 18 fence)
#pragma unroll
        for (int c = 0; c < 4; c++) {
            bf16x4 pk;
            pk[0] = (bf16)sc[c][0]; pk[1] = (bf16)sc[c][1];
            pk[2] = (bf16)sc[c][2]; pk[3] = (bf16)sc[c][3];
            *(bf16x4*)&P[wv][l15][16 * c + 4 * g] = pk;
        }
        asm volatile("s_waitcnt lgkmcnt(0)" ::: "memory");
        __builtin_amdgcn_sched_barrier(0);
        bf16x8 aP0 = *(const bf16x8*)&P[wv][l15][g * 8];
        bf16x8 aP1 = *(const bf16x8*)&P[wv][l15][32 + g * 8];
        // 8. PV
#pragma unroll
        for (int dt = 0; dt < 4; dt++) {
            O[dt] = __builtin_amdgcn_mfma_f32_16x16x32_bf16(aP0, bV[dt][0], O[dt], 0, 0, 0);
            O[dt] = __builtin_amdgcn_mfma_f32_16x16x32_bf16(aP1, bV[dt][1], O[dt], 0, 0, 0);
        }
    }

    // ---- epilogue ----
#pragma unroll
    for (int r = 0; r < 4; r++) {
        float lq = __shfl(lrun, 4 * g + r, 64);
        float inv = 1.0f / lq;
        int s = st0s + 4 * g + r;
        int token = s * BATCH + b;
#pragma unroll
        for (int dt = 0; dt < 4; dt++) {
            int h = nh * HDIM + dt * 16 + l15;
            ctx[(size_t)token * HID + h] = (bf16)(O[dt][r] * inv);
        }
    }
}

extern "C" void kernel_launch(void* const* d_in, const int* in_sizes, int n_in,
                              void* d_out, int out_size, void* d_ws, size_t ws_size,
                              hipStream_t stream) {
    const float* hidden = (const float*)d_in[0];
    const float* amask  = (const float*)d_in[1];
    const float* kmask  = (const float*)d_in[2];
    const float* Wq = (const float*)d_in[3];
    const float* bq = (const float*)d_in[4];
    const float* Wk = (const float*)d_in[5];
    const float* bk = (const float*)d_in[6];
    const float* Wv = (const float*)d_in[7];
    const float* bv = (const float*)d_in[8];
    const float* Wo = (const float*)d_in[9];
    const float* bo = (const float*)d_in[10];
    float* out = (float*)d_out;

    char* ws = (char*)d_ws;
    bf16* Xb   = (bf16*)(ws);                       // 8 MB  [4096][1024]
    bf16* Wcat = (bf16*)(ws + (8u  << 20));         // 6 MB  [3072][1024]
    bf16* Wob  = (bf16*)(ws + (14u << 20));         // 2 MB  [1024][1024]
    bf16* qh   = (bf16*)(ws + (16u << 20));         // 8 MB  [32][2048][64]
    bf16* kh   = (bf16*)(ws + (24u << 20));         // 8 MB
    bf16* vT   = (bf16*)(ws + (40u << 20));         // 8 MB  [32][64][2048]
    bf16* ctx  = (bf16*)(ws + (48u << 20));         // 8 MB  [4096][1024]

    cvt_f32_bf16<<<2048, 256, 0, stream>>>(hidden, Xb, NTOK * HID);
    cvt_f32_bf16<<<512, 256, 0, stream>>>(Wq, Wcat,              HID * HID);
    cvt_f32_bf16<<<512, 256, 0, stream>>>(Wk, Wcat + HID * HID,  HID * HID);
    cvt_f32_bf16<<<512, 256, 0, stream>>>(Wv, Wcat + 2 * HID * HID, HID * HID);
    cvt_f32_bf16<<<512, 256, 0, stream>>>(Wo, Wob, HID * HID);

    gemm_bt<<<dim3(24, 32), 256, 0, stream>>>(Xb, Wcat, NTOK, 3 * HID, HID, 0,
                                              bq, bk, bv, bo, qh, kh, vT, nullptr);
    attn<<<dim3(64, 16), 256, 0, stream>>>(qh, kh, vT, amask, kmask, ctx);
    gemm_bt<<<dim3(8, 32), 256, 0, stream>>>(ctx, Wob, NTOK, HID, HID, 1,
                                             bq, bk, bv, bo, qh, kh, vT, out);
}